// Round 6
// baseline (3156.301 us; speedup 1.0000x reference)
//
#include <hip/hip_runtime.h>
#include <hip/hip_bf16.h>

#define HH 500
#define NSEQ 2304
#define NGOALS 256
#define NHYPS 2048
#define LSEQ 128
#define NVOCAB 1000
#define NEG_SLOPE 0.01f
#define NPAD 2560
#define NROWS 160

typedef __attribute__((ext_vector_type(4)))  float f32x4;
typedef __attribute__((ext_vector_type(8)))  short short8;

__device__ __forceinline__ float sigm(float x) { return 1.0f / (1.0f + expf(-x)); }

__device__ __forceinline__ void gload_lds16(const void* g, void* l) {
    __builtin_amdgcn_global_load_lds(
        (const __attribute__((address_space(1))) unsigned int*)g,
        (__attribute__((address_space(3))) unsigned int*)l, 16, 0, 0);
}

// ---------- split conversions (verified r2-r5) ----------
__global__ void split_emb(const float* __restrict__ emb,
                          __hip_bfloat16* __restrict__ Eh, __hip_bfloat16* __restrict__ El)
{
    int idx = blockIdx.x * 256 + threadIdx.x;          // 1024*512
    if (idx >= 1024 * 512) return;
    int k = idx & 511, r = idx >> 9;
    float v = (r < NVOCAB && k < HH) ? emb[r * HH + k] : 0.0f;
    __hip_bfloat16 h = __float2bfloat16(v);
    Eh[idx] = h;
    El[idx] = __float2bfloat16(v - __bfloat162float(h));
}

__global__ void split_wih(const float* __restrict__ Wih,
                          __hip_bfloat16* __restrict__ Wh, __hip_bfloat16* __restrict__ Wl)
{
    int idx = blockIdx.x * 256 + threadIdx.x;          // 2000*512
    if (idx >= 2000 * 512) return;
    int k = idx & 511, r = idx >> 9;
    float v = (k < HH) ? Wih[r * HH + k] : 0.0f;
    __hip_bfloat16 h = __float2bfloat16(v);
    Wh[idx] = h;
    Wl[idx] = __float2bfloat16(v - __bfloat162float(h));
}

// Whh fp32 [2000][500] -> bf16 Wbi[u*4+g][512] interleaved, zero-padded
__global__ void conv_whh_i(const float* __restrict__ Whh, __hip_bfloat16* __restrict__ Wbi)
{
    int idx = blockIdx.x * 256 + threadIdx.x;          // 2048*512
    if (idx >= 2048 * 512) return;
    int k = idx & 511, row = idx >> 9;
    int u = row >> 2, g = row & 3;
    float v = (u < HH && k < HH) ? Whh[(g * HH + u) * HH + k] : 0.0f;
    Wbi[idx] = __float2bfloat16(v);
}

// ---------- T table: T4f[tok][u*4+g] fp32 (split-bf16 GEMM, verified r4/r5) ----------
__global__ __launch_bounds__(256) void tgemm_split(
    const __hip_bfloat16* __restrict__ Eh, const __hip_bfloat16* __restrict__ El,
    const __hip_bfloat16* __restrict__ Wh, const __hip_bfloat16* __restrict__ Wl,
    const float* __restrict__ bih, const float* __restrict__ bhh,
    float* __restrict__ T4f)
{
    __shared__ char lds[40960];
    int tid = threadIdx.x, w = tid >> 6, lane = tid & 63;
    int j0 = blockIdx.x * 16;
    int m0 = blockIdx.y * 64;
    int lrow = lane >> 3, cblk = (lane & 7) ^ lrow, r7 = lane & 7;
    const short* eh = (const short*)Eh; const short* el = (const short*)El;
    const short* wh = (const short*)Wh; const short* wl = (const short*)Wl;
    f32x4 acc = {};
    int arow = w * 16 + (lane & 15);

    auto STAGE = [&](int buf, int k0) {
        char* base = lds + buf * 20480;
        #pragma unroll
        for (int i = 0; i < 2; ++i) {
            int r = (w * 2 + i) * 8 + lrow;
            gload_lds16(eh + (size_t)(m0 + r) * 512 + k0 + cblk * 8, base + (w * 2 + i) * 1024);
            gload_lds16(el + (size_t)(m0 + r) * 512 + k0 + cblk * 8, base + 8192 + (w * 2 + i) * 1024);
        }
        {
            int half = w & 1;
            int r = half * 8 + lrow;
            const short* src = (w < 2) ? wh : wl;
            int off = (w < 2) ? 16384 : 18432;
            gload_lds16(src + (size_t)(j0 + r) * 512 + cblk * 8 + k0, base + off + half * 1024);
        }
    };

    STAGE(0, 0);
    __syncthreads();
    int cur = 0;
    for (int ch = 0; ch < 8; ++ch) {
        if (ch < 7) STAGE(cur ^ 1, (ch + 1) * 64);
        char* base = lds + cur * 20480;
        #pragma unroll
        for (int ks = 0; ks < 2; ++ks) {
            int blk = (ks * 4 + (lane >> 4)) ^ r7;
            short8 ah = *(const short8*)(base + arow * 128 + blk * 16);
            short8 al = *(const short8*)(base + 8192 + arow * 128 + blk * 16);
            short8 bh = *(const short8*)(base + 16384 + (lane & 15) * 128 + blk * 16);
            short8 bl = *(const short8*)(base + 18432 + (lane & 15) * 128 + blk * 16);
            acc = __builtin_amdgcn_mfma_f32_16x16x32_bf16(ah, bh, acc, 0, 0, 0);
            acc = __builtin_amdgcn_mfma_f32_16x16x32_bf16(ah, bl, acc, 0, 0, 0);
            acc = __builtin_amdgcn_mfma_f32_16x16x32_bf16(al, bh, acc, 0, 0, 0);
        }
        if (ch < 7) { __syncthreads(); cur ^= 1; }
    }
    int j = j0 + (lane & 15);
    int g = (j >= 1500) ? 3 : (j >= 1000) ? 2 : (j >= 500) ? 1 : 0;
    int u = j - g * 500;
    float bias = bih[j] + bhh[j];
    #pragma unroll
    for (int r = 0; r < 4; ++r) {
        int m = m0 + w * 16 + (lane >> 4) * 4 + r;
        if (m < NVOCAB) T4f[(size_t)m * 2048 + u * 4 + g] = acc[r] + bias;
    }
}

// ---------- LSTM step: 256 blocks (1/CU), 512 thr (8 waves), B in registers ----------
// Block tile: 160n x 128gc.  Wave (wr,wc): rows wr*80..+80, gc wc*32..+32.
// B (Wbi slice) in VGPRs (128/wave); LDS = A chunks only (2 x 40KB dbuf).
__global__ __launch_bounds__(512) void lstm_step6(
    const float* __restrict__ T4f,
    const int* __restrict__ goals, const int* __restrict__ hyps,
    const __hip_bfloat16* __restrict__ Wbi,
    const __hip_bfloat16* __restrict__ hin,
    __hip_bfloat16* __restrict__ hout,
    float* __restrict__ c, int tstep)
{
    extern __shared__ char smem[];          // 2*40960 A dbuf + 640 toks
    char* Ab[2] = { smem, smem + 40960 };
    int* toks = (int*)(smem + 81920);

    const int tid = threadIdx.x, w = tid >> 6, lane = tid & 63;
    const int wr = w >> 2, wc = w & 3;
    const int bx = blockIdx.x;              // ugrp
    const int n0 = blockIdx.y * NROWS;      // ngrp
    const int gcb = bx * 128 + wc * 32;
    const int l15 = lane & 15, l16 = lane >> 4;

    if (tid < NROWS) {
        int n = n0 + tid;
        toks[tid] = (n < NSEQ) ? ((n < NGOALS) ? goals[n * LSEQ + tstep]
                                               : hyps[(n - NGOALS) * LSEQ + tstep]) : 0;
    }

    // B slice -> registers: 2 colfrags x 16 k-slices (16B each)
    short8 breg[2][16];
    const short* wsrc = (const short*)Wbi;
    #pragma unroll
    for (int cf = 0; cf < 2; ++cf)
        #pragma unroll
        for (int ks = 0; ks < 16; ++ks)
            breg[cf][ks] = *(const short8*)(wsrc + (size_t)(gcb + cf * 16 + l15) * 512
                                                 + ks * 32 + l16 * 8);

    const short* hsrc = (const short*)hin;
    auto STAGE = [&](int buf, int ch) {     // A chunk: 160 rows x 128B, swizzled source
        #pragma unroll
        for (int i = 0; i < 5; ++i) {
            int row = (w * 5 + i) * 4 + l16;          // 0..159
            int sblk = l15 ^ (row & 7);
            gload_lds16(hsrc + (size_t)(n0 + row) * 512 + ch * 128 + sblk * 8,
                        Ab[buf] + (w * 5 + i) * 1024);
        }
    };

    f32x4 acc[5][2] = {};
    STAGE(0, 0);
    __syncthreads();
    for (int ch = 0; ch < 4; ++ch) {
        if (ch < 3) STAGE((ch + 1) & 1, ch + 1);
        char* A_ = Ab[ch & 1];
        #pragma unroll
        for (int ks4 = 0; ks4 < 4; ++ks4) {
            int ksg = ch * 4 + ks4;
            #pragma unroll
            for (int fr = 0; fr < 5; ++fr) {
                int row = wr * 80 + fr * 16 + l15;
                int slot = (ks4 * 4 + l16) ^ (row & 7);
                short8 a = *(const short8*)(A_ + row * 256 + slot * 16);
                acc[fr][0] = __builtin_amdgcn_mfma_f32_16x16x32_bf16(a, breg[0][ksg], acc[fr][0], 0, 0, 0);
                acc[fr][1] = __builtin_amdgcn_mfma_f32_16x16x32_bf16(a, breg[1][ksg], acc[fr][1], 0, 0, 0);
            }
        }
        __syncthreads();
    }

    // ---- epilogue: 4-lane gate butterfly (exact fp32), fused pointwise ----
    const int g = l15 & 3, ul = l15 >> 2;
    const bool odd1 = g & 1, hi = (g >> 1) & 1;
    #pragma unroll
    for (int fr = 0; fr < 5; ++fr)
    #pragma unroll
    for (int cf = 0; cf < 2; ++cf) {
        f32x4 v = acc[fr][cf];
        float e0 = __shfl_xor(v[0], 1), e1 = __shfl_xor(v[1], 1);
        float e2 = __shfl_xor(v[2], 1), e3 = __shfl_xor(v[3], 1);
        float a0 = odd1 ? v[1] : v[0], a1 = odd1 ? v[3] : v[2];
        float b0 = odd1 ? e1 : e0,     b1 = odd1 ? e3 : e2;
        float f0 = __shfl_xor(a0, 2), f1 = __shfl_xor(a1, 2);
        float f2 = __shfl_xor(b0, 2), f3 = __shfl_xor(b1, 2);
        float A = hi ? a1 : a0;   // gate g,   row r0+g
        float B = hi ? b1 : b0;   // gate g^1
        float C = hi ? f1 : f0;   // gate g^2
        float D = hi ? f3 : f2;   // gate g^3
        float gi = (g == 0) ? A : (g == 1) ? B : (g == 2) ? C : D;
        float gf = (g == 1) ? A : (g == 0) ? B : (g == 3) ? C : D;
        float gt = (g == 2) ? A : (g == 3) ? B : (g == 0) ? C : D;
        float go = (g == 3) ? A : (g == 2) ? B : (g == 1) ? C : D;
        int nl = wr * 80 + fr * 16 + l16 * 4 + g;
        int u  = bx * 32 + wc * 8 + cf * 4 + ul;
        if (u < HH) {
            f32x4 t4 = *(const f32x4*)(T4f + (size_t)toks[nl] * 2048 + (size_t)u * 4);
            gi += t4[0]; gf += t4[1]; gt += t4[2]; go += t4[3];
            float si = sigm(gi), sf = sigm(gf), so = sigm(go);
            size_t ci = (size_t)(n0 + nl) * 512 + u;
            float cv = sf * c[ci] + si * tanhf(gt);
            c[ci] = cv;
            hout[ci] = __float2bfloat16(so * tanhf(cv));
        }
    }
}

// ---------- fused tail: segsum + concat + 3 layers + rownorm (ILP-4 dot loops) ----------
__global__ __launch_bounds__(256) void tail_fused(
    const __hip_bfloat16* __restrict__ hfin, const int* __restrict__ segid,
    const float* __restrict__ W1, const float* __restrict__ b1,
    const float* __restrict__ W2, const float* __restrict__ b2,
    const float* __restrict__ Wf, const float* __restrict__ bf,
    float* __restrict__ out)
{
    __shared__ float x[1008];
    __shared__ float y[504];
    __shared__ float z[504];
    __shared__ int lohi[2];
    __shared__ float redw[4];
    __shared__ float rnorm;
    int r = blockIdx.x, tid = threadIdx.x;
    int lane = tid & 63, w = tid >> 6;

    if (tid < 2) {
        int target = r + tid;
        int lo = 0, hi = NHYPS;
        while (lo < hi) { int m = (lo + hi) >> 1; if (segid[m] < target) lo = m + 1; else hi = m; }
        lohi[tid] = lo;
    }
    for (int u = tid; u < HH; u += 256)
        x[u] = __bfloat162float(hfin[(size_t)r * 512 + u]);
    __syncthreads();
    int lo = lohi[0], hi = lohi[1];
    for (int u = tid; u < HH; u += 256) {
        float s = 0.f;
        for (int q = lo; q < hi; ++q)
            s += __bfloat162float(hfin[(size_t)(NGOALS + q) * 512 + u]);
        x[HH + u] = s;
    }
    __syncthreads();

    #define DOT_ILP4(WPTR, KLEN, XBUF, OUTEXPR, BIASV)                          \
    {                                                                            \
        const float* wr_ = (WPTR);                                               \
        float s0 = (BIASV), s1 = 0.f, s2 = 0.f, s3 = 0.f;                        \
        int k = 0;                                                               \
        for (; k + 16 <= (KLEN); k += 16) {                                      \
            f32x4 w0 = *(const f32x4*)(wr_ + k);                                 \
            f32x4 w1v = *(const f32x4*)(wr_ + k + 4);                            \
            f32x4 w2 = *(const f32x4*)(wr_ + k + 8);                             \
            f32x4 w3 = *(const f32x4*)(wr_ + k + 12);                            \
            s0 += w0[0]*XBUF[k]    + w0[1]*XBUF[k+1]  + w0[2]*XBUF[k+2]  + w0[3]*XBUF[k+3];  \
            s1 += w1v[0]*XBUF[k+4] + w1v[1]*XBUF[k+5] + w1v[2]*XBUF[k+6] + w1v[3]*XBUF[k+7]; \
            s2 += w2[0]*XBUF[k+8]  + w2[1]*XBUF[k+9]  + w2[2]*XBUF[k+10] + w2[3]*XBUF[k+11]; \
            s3 += w3[0]*XBUF[k+12] + w3[1]*XBUF[k+13] + w3[2]*XBUF[k+14] + w3[3]*XBUF[k+15]; \
        }                                                                        \
        for (; k < (KLEN); k += 4) {                                             \
            f32x4 wv = *(const f32x4*)(wr_ + k);                                 \
            s0 += wv[0]*XBUF[k] + wv[1]*XBUF[k+1] + wv[2]*XBUF[k+2] + wv[3]*XBUF[k+3]; \
        }                                                                        \
        float a_ = s0 + s1 + s2 + s3;                                            \
        OUTEXPR;                                                                 \
    }

    for (int o = tid; o < HH; o += 256)
        DOT_ILP4(W1 + (size_t)o * 1000, 1000, x,
                 y[o] = (a_ >= 0.f) ? a_ : NEG_SLOPE * a_, b1[o]);
    __syncthreads();
    for (int o = tid; o < HH; o += 256)
        DOT_ILP4(W2 + (size_t)o * 500, 500, y,
                 z[o] = (a_ >= 0.f) ? a_ : NEG_SLOPE * a_, b2[o]);
    __syncthreads();
    for (int o = tid; o < HH; o += 256)
        DOT_ILP4(Wf + (size_t)o * 500, 500, z, y[o] = a_, bf[o]);
    __syncthreads();
    float p = 0.f;
    for (int u = tid; u < HH; u += 256) p += y[u] * y[u];
    #pragma unroll
    for (int off = 32; off > 0; off >>= 1) p += __shfl_down(p, off);
    if (lane == 0) redw[w] = p;
    __syncthreads();
    if (tid == 0) rnorm = fmaxf(sqrtf(redw[0] + redw[1] + redw[2] + redw[3]), 1e-12f);
    __syncthreads();
    for (int u = tid; u < HH; u += 256) out[(size_t)r * HH + u] = y[u] / rnorm;
}

extern "C" void kernel_launch(void* const* d_in, const int* in_sizes, int n_in,
                              void* d_out, int out_size, void* d_ws, size_t ws_size,
                              hipStream_t stream)
{
    const int*   goals = (const int*)d_in[0];
    const int*   hyps  = (const int*)d_in[1];
    const int*   segid = (const int*)d_in[2];
    const float* emb   = (const float*)d_in[3];
    const float* Wih   = (const float*)d_in[4];
    const float* Whh   = (const float*)d_in[5];
    const float* bih   = (const float*)d_in[6];
    const float* bhh   = (const float*)d_in[7];
    const float* W1    = (const float*)d_in[8];
    const float* b1    = (const float*)d_in[9];
    const float* W2    = (const float*)d_in[10];
    const float* b2    = (const float*)d_in[11];
    const float* Wf    = (const float*)d_in[12];
    const float* bf    = (const float*)d_in[13];
    float* out = (float*)d_out;

    char* base = (char*)d_ws;
    float*          T4f = (float*)(base + 0);                   //  8,192,000
    __hip_bfloat16* Wbi = (__hip_bfloat16*)(base + 8192000);    //  2,097,152
    __hip_bfloat16* hb0 = (__hip_bfloat16*)(base + 10289152);   //  2,621,440 (2560x512)
    __hip_bfloat16* hb1 = (__hip_bfloat16*)(base + 12910592);   //  2,621,440
    float*          c   = (float*)(base + 15532032);            //  5,242,880 (2560x512)
    // transient aliases (consumed by tgemm_split before hb/c memsets)
    __hip_bfloat16* Eh = (__hip_bfloat16*)(base + 10289152);    // in hb0, 1,048,576
    __hip_bfloat16* El = (__hip_bfloat16*)(base + 11337728);    // in hb0, 1,048,576
    __hip_bfloat16* Wh = (__hip_bfloat16*)(base + 12910592);    // in hb1, 2,048,000
    __hip_bfloat16* Wl = (__hip_bfloat16*)(base + 15532032);    // in c,   2,048,000

    split_emb<<<2048, 256, 0, stream>>>(emb, Eh, El);
    split_wih<<<4000, 256, 0, stream>>>(Wih, Wh, Wl);
    conv_whh_i<<<4096, 256, 0, stream>>>(Whh, Wbi);
    hipMemsetAsync(T4f, 0, 8192000, stream);
    tgemm_split<<<dim3(125, 16), 256, 0, stream>>>(Eh, El, Wh, Wl, bih, bhh, T4f);

    hipMemsetAsync(hb0, 0, 2621440, stream);
    hipMemsetAsync(hb1, 0, 2621440, stream);
    hipMemsetAsync(c,   0, 5242880, stream);

    hipFuncSetAttribute((const void*)lstm_step6,
                        hipFuncAttributeMaxDynamicSharedMemorySize, 82560);

    __hip_bfloat16* hb[2] = { hb0, hb1 };
    for (int t = 0; t < LSEQ; ++t) {
        lstm_step6<<<dim3(16, 16), 512, 82560, stream>>>(
            T4f, goals, hyps, Wbi, hb[t & 1], hb[(t + 1) & 1], c, t);
    }
    __hip_bfloat16* hfin = hb0;   // LSEQ even -> final lands in hb0

    tail_fused<<<NGOALS, 256, 0, stream>>>(hfin, segid, W1, b1, W2, b2, Wf, bf, out);
}

// Round 7
// 3044.661 us; speedup vs baseline: 1.0367x; 1.0367x over previous
//
#include <hip/hip_runtime.h>
#include <hip/hip_bf16.h>

#define HH 500
#define NSEQ 2304
#define NGOALS 256
#define NHYPS 2048
#define LSEQ 128
#define NVOCAB 1000
#define NEG_SLOPE 0.01f
#define NPAD 2560
#define NROWS 160

typedef __attribute__((ext_vector_type(4)))  float f32x4;
typedef __attribute__((ext_vector_type(8)))  short short8;

__device__ __forceinline__ float sigm(float x) { return 1.0f / (1.0f + expf(-x)); }

__device__ __forceinline__ void gload_lds16(const void* g, void* l) {
    __builtin_amdgcn_global_load_lds(
        (const __attribute__((address_space(1))) unsigned int*)g,
        (__attribute__((address_space(3))) unsigned int*)l, 16, 0, 0);
}

// ---------- split conversions (verified r2-r6) ----------
__global__ void split_emb(const float* __restrict__ emb,
                          __hip_bfloat16* __restrict__ Eh, __hip_bfloat16* __restrict__ El)
{
    int idx = blockIdx.x * 256 + threadIdx.x;          // 1024*512
    if (idx >= 1024 * 512) return;
    int k = idx & 511, r = idx >> 9;
    float v = (r < NVOCAB && k < HH) ? emb[r * HH + k] : 0.0f;
    __hip_bfloat16 h = __float2bfloat16(v);
    Eh[idx] = h;
    El[idx] = __float2bfloat16(v - __bfloat162float(h));
}

__global__ void split_wih(const float* __restrict__ Wih,
                          __hip_bfloat16* __restrict__ Wh, __hip_bfloat16* __restrict__ Wl)
{
    int idx = blockIdx.x * 256 + threadIdx.x;          // 2000*512
    if (idx >= 2000 * 512) return;
    int k = idx & 511, r = idx >> 9;
    float v = (k < HH) ? Wih[r * HH + k] : 0.0f;
    __hip_bfloat16 h = __float2bfloat16(v);
    Wh[idx] = h;
    Wl[idx] = __float2bfloat16(v - __bfloat162float(h));
}

// Whh fp32 [2000][500] -> bf16 Wbi[u*4+g][512] interleaved, zero-padded
__global__ void conv_whh_i(const float* __restrict__ Whh, __hip_bfloat16* __restrict__ Wbi)
{
    int idx = blockIdx.x * 256 + threadIdx.x;          // 2048*512
    if (idx >= 2048 * 512) return;
    int k = idx & 511, row = idx >> 9;
    int u = row >> 2, g = row & 3;
    float v = (u < HH && k < HH) ? Whh[(g * HH + u) * HH + k] : 0.0f;
    Wbi[idx] = __float2bfloat16(v);
}

// ---------- T table: T4f[tok][u*4+g] fp32 (split-bf16 GEMM, verified r4-r6) ----------
__global__ __launch_bounds__(256) void tgemm_split(
    const __hip_bfloat16* __restrict__ Eh, const __hip_bfloat16* __restrict__ El,
    const __hip_bfloat16* __restrict__ Wh, const __hip_bfloat16* __restrict__ Wl,
    const float* __restrict__ bih, const float* __restrict__ bhh,
    float* __restrict__ T4f)
{
    __shared__ char lds[40960];
    int tid = threadIdx.x, w = tid >> 6, lane = tid & 63;
    int j0 = blockIdx.x * 16;
    int m0 = blockIdx.y * 64;
    int lrow = lane >> 3, cblk = (lane & 7) ^ lrow, r7 = lane & 7;
    const short* eh = (const short*)Eh; const short* el = (const short*)El;
    const short* wh = (const short*)Wh; const short* wl = (const short*)Wl;
    f32x4 acc = {};
    int arow = w * 16 + (lane & 15);

    auto STAGE = [&](int buf, int k0) {
        char* base = lds + buf * 20480;
        #pragma unroll
        for (int i = 0; i < 2; ++i) {
            int r = (w * 2 + i) * 8 + lrow;
            gload_lds16(eh + (size_t)(m0 + r) * 512 + k0 + cblk * 8, base + (w * 2 + i) * 1024);
            gload_lds16(el + (size_t)(m0 + r) * 512 + k0 + cblk * 8, base + 8192 + (w * 2 + i) * 1024);
        }
        {
            int half = w & 1;
            int r = half * 8 + lrow;
            const short* src = (w < 2) ? wh : wl;
            int off = (w < 2) ? 16384 : 18432;
            gload_lds16(src + (size_t)(j0 + r) * 512 + cblk * 8 + k0, base + off + half * 1024);
        }
    };

    STAGE(0, 0);
    __syncthreads();
    int cur = 0;
    for (int ch = 0; ch < 8; ++ch) {
        if (ch < 7) STAGE(cur ^ 1, (ch + 1) * 64);
        char* base = lds + cur * 20480;
        #pragma unroll
        for (int ks = 0; ks < 2; ++ks) {
            int blk = (ks * 4 + (lane >> 4)) ^ r7;
            short8 ah = *(const short8*)(base + arow * 128 + blk * 16);
            short8 al = *(const short8*)(base + 8192 + arow * 128 + blk * 16);
            short8 bh = *(const short8*)(base + 16384 + (lane & 15) * 128 + blk * 16);
            short8 bl = *(const short8*)(base + 18432 + (lane & 15) * 128 + blk * 16);
            acc = __builtin_amdgcn_mfma_f32_16x16x32_bf16(ah, bh, acc, 0, 0, 0);
            acc = __builtin_amdgcn_mfma_f32_16x16x32_bf16(ah, bl, acc, 0, 0, 0);
            acc = __builtin_amdgcn_mfma_f32_16x16x32_bf16(al, bh, acc, 0, 0, 0);
        }
        if (ch < 7) { __syncthreads(); cur ^= 1; }
    }
    int j = j0 + (lane & 15);
    int g = (j >= 1500) ? 3 : (j >= 1000) ? 2 : (j >= 500) ? 1 : 0;
    int u = j - g * 500;
    float bias = bih[j] + bhh[j];
    #pragma unroll
    for (int r = 0; r < 4; ++r) {
        int m = m0 + w * 16 + (lane >> 4) * 4 + r;
        if (m < NVOCAB) T4f[(size_t)m * 2048 + u * 4 + g] = acc[r] + bias;
    }
}

// ---------- LSTM step: 256 blocks (1/CU), 512 thr (8 waves), B truly in registers ----------
// Block tile: 160n x 128gc.  Wave (wr,wc): rows wr*80..+80, gc wc*32..+32.
// FIX vs r6: ch loop fully unrolled -> breg[][] indices compile-time (no scratch spill),
// __launch_bounds__(512,2) pins VGPR <= 256.
__global__ __launch_bounds__(512, 2) void lstm_step7(
    const float* __restrict__ T4f,
    const int* __restrict__ goals, const int* __restrict__ hyps,
    const __hip_bfloat16* __restrict__ Wbi,
    const __hip_bfloat16* __restrict__ hin,
    __hip_bfloat16* __restrict__ hout,
    float* __restrict__ c, int tstep)
{
    extern __shared__ char smem[];          // 2*40960 A dbuf + 640 toks
    char* Ab0 = smem;
    char* Ab1 = smem + 40960;
    int* toks = (int*)(smem + 81920);

    const int tid = threadIdx.x, w = tid >> 6, lane = tid & 63;
    const int wr = w >> 2, wc = w & 3;
    const int bx = blockIdx.x;              // ugrp
    const int n0 = blockIdx.y * NROWS;      // ngrp
    const int gcb = bx * 128 + wc * 32;
    const int l15 = lane & 15, l16 = lane >> 4;

    if (tid < NROWS) {
        int n = n0 + tid;
        toks[tid] = (n < NSEQ) ? ((n < NGOALS) ? goals[n * LSEQ + tstep]
                                               : hyps[(n - NGOALS) * LSEQ + tstep]) : 0;
    }

    // B slice -> registers: 2 colfrags x 16 k-slices (16B each) = 128 VGPR
    short8 breg[2][16];
    const short* wsrc = (const short*)Wbi;
    #pragma unroll
    for (int cf = 0; cf < 2; ++cf)
        #pragma unroll
        for (int ks = 0; ks < 16; ++ks)
            breg[cf][ks] = *(const short8*)(wsrc + (size_t)(gcb + cf * 16 + l15) * 512
                                                 + ks * 32 + l16 * 8);

    const short* hsrc = (const short*)hin;
    auto STAGE = [&](char* buf, int ch) {   // A chunk: 160 rows x 256B, swizzled source
        #pragma unroll
        for (int i = 0; i < 5; ++i) {
            int row = (w * 5 + i) * 4 + l16;          // 0..159
            int sblk = l15 ^ (row & 7);
            gload_lds16(hsrc + (size_t)(n0 + row) * 512 + ch * 128 + sblk * 8,
                        buf + (w * 5 + i) * 1024);
        }
    };

    f32x4 acc[5][2] = {};
    STAGE(Ab0, 0);
    __syncthreads();
    #pragma unroll
    for (int ch = 0; ch < 4; ++ch) {
        char* A_ = (ch & 1) ? Ab1 : Ab0;
        char* N_ = (ch & 1) ? Ab0 : Ab1;
        if (ch < 3) STAGE(N_, ch + 1);
        #pragma unroll
        for (int ks4 = 0; ks4 < 4; ++ks4) {
            const int ksg = ch * 4 + ks4;   // compile-time: breg stays in VGPRs
            #pragma unroll
            for (int fr = 0; fr < 5; ++fr) {
                int row = wr * 80 + fr * 16 + l15;
                int slot = (ks4 * 4 + l16) ^ (row & 7);
                short8 a = *(const short8*)(A_ + row * 256 + slot * 16);
                acc[fr][0] = __builtin_amdgcn_mfma_f32_16x16x32_bf16(a, breg[0][ksg], acc[fr][0], 0, 0, 0);
                acc[fr][1] = __builtin_amdgcn_mfma_f32_16x16x32_bf16(a, breg[1][ksg], acc[fr][1], 0, 0, 0);
            }
        }
        __syncthreads();
    }

    // ---- epilogue: 4-lane gate butterfly (exact fp32, verified r6), fused pointwise ----
    const int g = l15 & 3, ul = l15 >> 2;
    const bool odd1 = g & 1, hi = (g >> 1) & 1;
    #pragma unroll
    for (int fr = 0; fr < 5; ++fr)
    #pragma unroll
    for (int cf = 0; cf < 2; ++cf) {
        f32x4 v = acc[fr][cf];
        float e0 = __shfl_xor(v[0], 1), e1 = __shfl_xor(v[1], 1);
        float e2 = __shfl_xor(v[2], 1), e3 = __shfl_xor(v[3], 1);
        float a0 = odd1 ? v[1] : v[0], a1 = odd1 ? v[3] : v[2];
        float b0 = odd1 ? e1 : e0,     b1 = odd1 ? e3 : e2;
        float f0 = __shfl_xor(a0, 2), f1 = __shfl_xor(a1, 2);
        float f2 = __shfl_xor(b0, 2), f3 = __shfl_xor(b1, 2);
        float A = hi ? a1 : a0;   // gate g
        float B = hi ? b1 : b0;   // gate g^1
        float C = hi ? f1 : f0;   // gate g^2
        float D = hi ? f3 : f2;   // gate g^3
        float gi = (g == 0) ? A : (g == 1) ? B : (g == 2) ? C : D;
        float gf = (g == 1) ? A : (g == 0) ? B : (g == 3) ? C : D;
        float gt = (g == 2) ? A : (g == 3) ? B : (g == 0) ? C : D;
        float go = (g == 3) ? A : (g == 2) ? B : (g == 1) ? C : D;
        int nl = wr * 80 + fr * 16 + l16 * 4 + g;
        int u  = bx * 32 + wc * 8 + cf * 4 + ul;
        if (u < HH) {
            f32x4 t4 = *(const f32x4*)(T4f + (size_t)toks[nl] * 2048 + (size_t)u * 4);
            gi += t4[0]; gf += t4[1]; gt += t4[2]; go += t4[3];
            float si = sigm(gi), sf = sigm(gf), so = sigm(go);
            size_t ci = (size_t)(n0 + nl) * 512 + u;
            float cv = sf * c[ci] + si * tanhf(gt);
            c[ci] = cv;
            hout[ci] = __float2bfloat16(so * tanhf(cv));
        }
    }
}

// ---------- fused tail (r5 version, VGPR 32): segsum + concat + 3 layers + rownorm ----------
__global__ __launch_bounds__(256) void tail_fused(
    const __hip_bfloat16* __restrict__ hfin, const int* __restrict__ segid,
    const float* __restrict__ W1, const float* __restrict__ b1,
    const float* __restrict__ W2, const float* __restrict__ b2,
    const float* __restrict__ Wf, const float* __restrict__ bf,
    float* __restrict__ out)
{
    __shared__ float x[1008];
    __shared__ float y[504];
    __shared__ float z[504];
    __shared__ int lohi[2];
    __shared__ float redw[4];
    __shared__ float rnorm;
    int r = blockIdx.x, tid = threadIdx.x;
    int lane = tid & 63, w = tid >> 6;

    if (tid < 2) {
        int target = r + tid;
        int lo = 0, hi = NHYPS;
        while (lo < hi) { int m = (lo + hi) >> 1; if (segid[m] < target) lo = m + 1; else hi = m; }
        lohi[tid] = lo;
    }
    for (int u = tid; u < HH; u += 256)
        x[u] = __bfloat162float(hfin[(size_t)r * 512 + u]);
    __syncthreads();
    int lo = lohi[0], hi = lohi[1];
    for (int u = tid; u < HH; u += 256) {
        float s = 0.f;
        for (int q = lo; q < hi; ++q)
            s += __bfloat162float(hfin[(size_t)(NGOALS + q) * 512 + u]);
        x[HH + u] = s;
    }
    __syncthreads();
    for (int o = tid; o < HH; o += 256) {
        const float* wr = W1 + (size_t)o * 1000;
        float a = b1[o];
        for (int k = 0; k < 1000; k += 4) {
            f32x4 wv = *(const f32x4*)(wr + k);
            a += wv[0] * x[k] + wv[1] * x[k+1] + wv[2] * x[k+2] + wv[3] * x[k+3];
        }
        y[o] = (a >= 0.f) ? a : NEG_SLOPE * a;
    }
    __syncthreads();
    for (int o = tid; o < HH; o += 256) {
        const float* wr = W2 + (size_t)o * 500;
        float a = b2[o];
        for (int k = 0; k < 500; k += 4) {
            f32x4 wv = *(const f32x4*)(wr + k);
            a += wv[0] * y[k] + wv[1] * y[k+1] + wv[2] * y[k+2] + wv[3] * y[k+3];
        }
        z[o] = (a >= 0.f) ? a : NEG_SLOPE * a;
    }
    __syncthreads();
    for (int o = tid; o < HH; o += 256) {
        const float* wr = Wf + (size_t)o * 500;
        float a = bf[o];
        for (int k = 0; k < 500; k += 4) {
            f32x4 wv = *(const f32x4*)(wr + k);
            a += wv[0] * z[k] + wv[1] * z[k+1] + wv[2] * z[k+2] + wv[3] * z[k+3];
        }
        y[o] = a;
    }
    __syncthreads();
    float p = 0.f;
    for (int u = tid; u < HH; u += 256) p += y[u] * y[u];
    #pragma unroll
    for (int off = 32; off > 0; off >>= 1) p += __shfl_down(p, off);
    if (lane == 0) redw[w] = p;
    __syncthreads();
    if (tid == 0) rnorm = fmaxf(sqrtf(redw[0] + redw[1] + redw[2] + redw[3]), 1e-12f);
    __syncthreads();
    for (int u = tid; u < HH; u += 256) out[(size_t)r * HH + u] = y[u] / rnorm;
}

extern "C" void kernel_launch(void* const* d_in, const int* in_sizes, int n_in,
                              void* d_out, int out_size, void* d_ws, size_t ws_size,
                              hipStream_t stream)
{
    const int*   goals = (const int*)d_in[0];
    const int*   hyps  = (const int*)d_in[1];
    const int*   segid = (const int*)d_in[2];
    const float* emb   = (const float*)d_in[3];
    const float* Wih   = (const float*)d_in[4];
    const float* Whh   = (const float*)d_in[5];
    const float* bih   = (const float*)d_in[6];
    const float* bhh   = (const float*)d_in[7];
    const float* W1    = (const float*)d_in[8];
    const float* b1    = (const float*)d_in[9];
    const float* W2    = (const float*)d_in[10];
    const float* b2    = (const float*)d_in[11];
    const float* Wf    = (const float*)d_in[12];
    const float* bf    = (const float*)d_in[13];
    float* out = (float*)d_out;

    char* base = (char*)d_ws;
    float*          T4f = (float*)(base + 0);                   //  8,192,000
    __hip_bfloat16* Wbi = (__hip_bfloat16*)(base + 8192000);    //  2,097,152
    __hip_bfloat16* hb0 = (__hip_bfloat16*)(base + 10289152);   //  2,621,440 (2560x512)
    __hip_bfloat16* hb1 = (__hip_bfloat16*)(base + 12910592);   //  2,621,440
    float*          c   = (float*)(base + 15532032);            //  5,242,880 (2560x512)
    // transient aliases (consumed by tgemm_split before hb/c memsets)
    __hip_bfloat16* Eh = (__hip_bfloat16*)(base + 10289152);    // in hb0, 1,048,576
    __hip_bfloat16* El = (__hip_bfloat16*)(base + 11337728);    // in hb0, 1,048,576
    __hip_bfloat16* Wh = (__hip_bfloat16*)(base + 12910592);    // in hb1, 2,048,000
    __hip_bfloat16* Wl = (__hip_bfloat16*)(base + 15532032);    // in c,   2,048,000

    split_emb<<<2048, 256, 0, stream>>>(emb, Eh, El);
    split_wih<<<4000, 256, 0, stream>>>(Wih, Wh, Wl);
    conv_whh_i<<<4096, 256, 0, stream>>>(Whh, Wbi);
    hipMemsetAsync(T4f, 0, 8192000, stream);
    tgemm_split<<<dim3(125, 16), 256, 0, stream>>>(Eh, El, Wh, Wl, bih, bhh, T4f);

    hipMemsetAsync(hb0, 0, 2621440, stream);
    hipMemsetAsync(hb1, 0, 2621440, stream);
    hipMemsetAsync(c,   0, 5242880, stream);

    hipFuncSetAttribute((const void*)lstm_step7,
                        hipFuncAttributeMaxDynamicSharedMemorySize, 82560);

    __hip_bfloat16* hb[2] = { hb0, hb1 };
    for (int t = 0; t < LSEQ; ++t) {
        lstm_step7<<<dim3(16, 16), 512, 82560, stream>>>(
            T4f, goals, hyps, Wbi, hb[t & 1], hb[(t + 1) & 1], c, t);
    }
    __hip_bfloat16* hfin = hb0;   // LSEQ even -> final lands in hb0

    tail_fused<<<NGOALS, 256, 0, stream>>>(hfin, segid, W1, b1, W2, b2, Wf, bf, out);
}